// Round 4
// baseline (44.628 us; speedup 1.0000x reference)
//
#include <hip/hip_runtime.h>

// VQ argmin: for each weight w[i], indices[i] = argmin_k (w[i] - cb[k])^2,
// first-index tie-break (matches jnp.argmin).
//
// Structure (R3 lesson): the sort-once + 11-step-binary-search pipeline is
// ~2 us (proven R2); the per-block bucket build was 16 us. The workspace
// cannot be used (touching d_ws serializes a 256 MiB poison-fill, ~39 us,
// into the timed path — R2 evidence). So the 8 KB sorted-codebook stash
// lives in the OUT buffer itself (out[0..2047]), handed off across three
// stream-ordered launches with no cross-block races:
//   k1: rank-sort codebook -> stash at out[0..2047]
//   k2: answers for gids 2048..N-1 (+ y)   [reads stash, never writes it]
//   k3: single block: load stash to LDS, barrier, overwrite out[0..2047]
//       with the real answers               [safe: one block, stream-ordered]
//
// Exactness (identical to the R2 kernel that passed absmax 0.0):
//  - dist computed exactly as reference: fl(fl(x-c)^2).
//  - fl((x-c)^2) is monotone in |x-c|, so the argmin is a neighbor of the
//    insertion point and all fp32-distance ties form a contiguous run in
//    sorted order; min ORIGINAL index over that run == jnp.argmin tie-break.
//  - lower_bound via uniform power-of-2 steps: 10 steps give min(L,1023),
//    one fix-up comparison resolves L==1024. All LDS indices in-bounds.
//  - NaN x: no candidate accepted -> sentinel -> 0 (np.argmin all-NaN row).

#define N_W   262144
#define K_CB  1024
#define STASH (2 * K_CB)   // ints: [0..1023]=sorted value bits, [1024..2047]=orig idx

__device__ __forceinline__ float dsq(float x, float c) {
    // Must match reference numerics exactly: subtract then square, fp32 RN.
    float d = x - c;
    return d * d;
}

__device__ __forceinline__ int nearest_idx(float x, const float* sv, const int* si) {
    // Uniform-step lower_bound: p == min(L, 1023) after 10 steps; fix-up
    // handles the all-less case (p -> 1024). 11 comparisons total.
    int p = 0;
    #pragma unroll
    for (int step = K_CB >> 1; step >= 1; step >>= 1) {
        if (sv[p + step - 1] < x) p += step;
    }
    if (p == K_CB - 1 && sv[K_CB - 1] < x) p = K_CB;

    const float INF = __builtin_inff();
    float dl = (p > 0)    ? dsq(x, sv[p - 1]) : INF;
    float dr = (p < K_CB) ? dsq(x, sv[p])     : INF;
    float dmin = fminf(dl, dr);

    // Min original index over the contiguous equality run (run ~1 typ.).
    int mi = 0x7fffffff;
    for (int i = p - 1; i >= 0; --i) {
        if (dsq(x, sv[i]) != dmin) break;
        mi = min(mi, si[i]);
    }
    for (int i = p; i < K_CB; ++i) {
        if (dsq(x, sv[i]) != dmin) break;
        mi = min(mi, si[i]);
    }
    return (mi == 0x7fffffff) ? 0 : mi;
}

// ---------------------------------------------------------------------------
// k1: stable rank-sort of the codebook -> stash in out[0..2047].
// 1024 threads (4 x 256); rank = #{j : (cj,j) < (c,tid)} is a permutation.
// ---------------------------------------------------------------------------
__global__ __launch_bounds__(256) void vq_rank_sort_kernel(
    const float* __restrict__ cb,
    int* __restrict__ out)
{
    __shared__ float scb[K_CB];
    for (int i = threadIdx.x; i < K_CB; i += 256) scb[i] = cb[i];
    __syncthreads();

    int tid = blockIdx.x * 256 + threadIdx.x;   // 0..1023
    float c = scb[tid];
    int rank = 0;
    #pragma unroll 16
    for (int j = 0; j < K_CB; ++j) {
        float cj = scb[j];
        rank += (int)((cj < c) || (cj == c && j < tid));
    }
    out[rank]        = __float_as_int(c);  // sorted values (bit-cast)
    out[K_CB + rank] = tid;                // original indices (stable)
}

// ---------------------------------------------------------------------------
// k2: main search, gids 2048..N_W-1. Reads stash from out, never writes it.
// ---------------------------------------------------------------------------
__global__ __launch_bounds__(256) void vq_search_main(
    const float* __restrict__ w,
    const int* __restrict__ y,
    int* out)                       // aliased read (stash) + write (answers)
{
    __shared__ float sv[K_CB];
    __shared__ int   si[K_CB];
    const int t = threadIdx.x;

    // Vectorized stash load: 2048 ints = 512 int4; 256 threads x 2 int4.
    const int4* st4 = reinterpret_cast<const int4*>(out);
    int4 v = st4[t];        // sval bits
    int4 u = st4[256 + t];  // sidx
    sv[4 * t + 0] = __int_as_float(v.x);
    sv[4 * t + 1] = __int_as_float(v.y);
    sv[4 * t + 2] = __int_as_float(v.z);
    sv[4 * t + 3] = __int_as_float(v.w);
    si[4 * t + 0] = u.x;
    si[4 * t + 1] = u.y;
    si[4 * t + 2] = u.z;
    si[4 * t + 3] = u.w;
    __syncthreads();

    int gid = STASH + blockIdx.x * 256 + t;
    float x = w[gid];
    out[gid] = nearest_idx(x, sv, si);

    if (gid == STASH) out[N_W] = y[0];  // pass-through scalar
}

// ---------------------------------------------------------------------------
// k3: fix-up, single block of 1024. Loads stash to LDS, barrier, then
// overwrites out[0..2047] with real answers. No cross-block race possible.
// ---------------------------------------------------------------------------
__global__ __launch_bounds__(1024) void vq_fixup(
    const float* __restrict__ w,
    int* out)
{
    __shared__ float sv[K_CB];
    __shared__ int   si[K_CB];
    const int t = threadIdx.x;     // 0..1023

    sv[t] = __int_as_float(out[t]);
    si[t] = out[K_CB + t];
    __syncthreads();               // all stash reads complete before any write

    float x0 = w[t];
    float x1 = w[t + K_CB];
    int r0 = nearest_idx(x0, sv, si);
    int r1 = nearest_idx(x1, sv, si);
    out[t]        = r0;
    out[t + K_CB] = r1;
}

extern "C" void kernel_launch(void* const* d_in, const int* in_sizes, int n_in,
                              void* d_out, int out_size, void* d_ws, size_t ws_size,
                              hipStream_t stream) {
    const float* w  = (const float*)d_in[0];
    const float* cb = (const float*)d_in[1]; // (K,1) contiguous == K floats
    const int*   y  = (const int*)d_in[2];
    int* out = (int*)d_out;

    // Deliberately NOT touching d_ws: harness serializes a 256 MiB poison
    // fill (~39 us at 86% HBM peak) into the timed path when ws is used.
    (void)d_ws; (void)ws_size;

    vq_rank_sort_kernel<<<K_CB / 256, 256, 0, stream>>>(cb, out);          // 4 blocks
    vq_search_main<<<(N_W - STASH) / 256, 256, 0, stream>>>(w, y, out);    // 1016 blocks
    vq_fixup<<<1, 1024, 0, stream>>>(w, out);                              // 1 block
}

// Round 5
// 20.674 us; speedup vs baseline: 2.1587x; 2.1587x over previous
//
#include <hip/hip_runtime.h>

// VQ argmin: for each weight w[i], indices[i] = argmin_k (w[i] - cb[k])^2,
// first-index tie-break (matches jnp.argmin).
//
// R4 lesson: per-launch overhead in this harness is ~14 us and does NOT
// pipeline within an iteration -- 3 launches cost ~42 us regardless of
// kernel time. (R0 42/1L, R2 41/2L+fill, R3 16/1L, R4 44.6/3L all fit
// dur = max(GPU time, 14 x n_launches).) Also: touching d_ws serializes a
// 256 MiB poison fill (~39 us) into the timed path (R2).
// => ONE launch, no workspace, and the cheapest possible per-block build.
//
// Design: 1024 blocks x 256 threads, 1 weight/thread, 4 cb entries/thread
// (kept in registers). Each block builds a bucket (counting) structure over
// a FIXED value grid [-4.2, 4.2] x 256 buckets in LDS -- no min/max
// reduction, 4 cheap barriers on a 4-wave block -- then each thread scans
// its weight's bucket and expands outward with a conservative prune.
//
// Exactness (distribution-independent; fixed grid only affects speed):
//  - dist computed exactly as reference: fl(fl(x-c)^2).
//  - End buckets are clamped, so out-of-range values land in bucket 0/255;
//    the left-prune bound "all values in buckets <= dl are <= edge" and the
//    right-prune bound both remain true for clamped values (they are even
//    farther out). Prune edge carries ONE FULL BUCKET of slack (~0.033),
//    orders of magnitude beyond any ulp slop in fp bucket assignment, and
//    prunes only on fl(gap^2) > best STRICTLY (monotone rounding) -- so no
//    entry whose distance ties the final minimum is ever skipped.
//  - Surviving candidates compared with explicit (d, original_index)
//    lexicographic order -> atomic scatter order inside a bucket is
//    irrelevant; jnp.argmin first-index tie-break reproduced exactly.
//  - NaN x: cvt NaN->0 picks bucket 0, no candidate ever accepted (NaN
//    compares false), prune never fires (NaN > 0 false) -> walks all
//    buckets, returns sentinel->0 == np.argmin on an all-NaN row.
//  - Degenerate codebook (all equal / tiny range): all entries in one
//    bucket; that bucket is scanned exactly; still correct, just slower.

#define N_W  262144
#define K_CB 1024
#define NB   256
#define BLK  256
#define GRID (N_W / BLK)        // 1024 blocks

#define GLO   (-4.2f)
#define GRANGE (8.4f)

__device__ __forceinline__ float dsq(float x, float c) {
    // Must match reference numerics exactly: subtract then square, fp32 RN.
    float d = x - c;
    return d * d;
}

__global__ __launch_bounds__(BLK) void vq_grid_kernel(
    const float* __restrict__ w,
    const float* __restrict__ cb,
    const int* __restrict__ y,
    int* __restrict__ out)
{
    __shared__ float bval[K_CB];     // bucketed codebook values
    __shared__ int   bidx[K_CB];     // their original indices
    __shared__ int   hist[NB];
    __shared__ int   bstart[NB + 1];
    __shared__ int   cursor[NB];

    const int t   = threadIdx.x;          // 0..255
    const int gid = blockIdx.x * BLK + t; // exact cover of N_W

    const float inv = (float)NB / GRANGE; // buckets are a fixed grid
    const float wdt = GRANGE / (float)NB;

    // Issue global loads up front (latency overlaps the LDS zeroing).
    float x = w[gid];
    const float4 c4 = reinterpret_cast<const float4*>(cb)[t]; // cb[4t..4t+3]

    hist[t] = 0;
    __syncthreads();                                   // B1

    // ---- histogram (bucket ids from registers) ----
    int b0 = min(max((int)((c4.x - GLO) * inv), 0), NB - 1);
    int b1 = min(max((int)((c4.y - GLO) * inv), 0), NB - 1);
    int b2 = min(max((int)((c4.z - GLO) * inv), 0), NB - 1);
    int b3 = min(max((int)((c4.w - GLO) * inv), 0), NB - 1);
    atomicAdd(&hist[b0], 1);
    atomicAdd(&hist[b1], 1);
    atomicAdd(&hist[b2], 1);
    atomicAdd(&hist[b3], 1);
    __syncthreads();                                   // B2

    // ---- exclusive prefix over 256 buckets (wave 0, shfl scan) ----
    if (t < 64) {
        int h0 = hist[4 * t + 0], h1 = hist[4 * t + 1];
        int h2 = hist[4 * t + 2], h3 = hist[4 * t + 3];
        int s1 = h0 + h1, s2 = s1 + h2, tot = s2 + h3;
        int inc = tot;
        #pragma unroll
        for (int off = 1; off < 64; off <<= 1) {
            int v = __shfl_up(inc, off);
            if (t >= off) inc += v;
        }
        int exc = inc - tot;
        bstart[4 * t + 0] = exc;      cursor[4 * t + 0] = exc;
        bstart[4 * t + 1] = exc + h0; cursor[4 * t + 1] = exc + h0;
        bstart[4 * t + 2] = exc + s1; cursor[4 * t + 2] = exc + s1;
        bstart[4 * t + 3] = exc + s2; cursor[4 * t + 3] = exc + s2;
        if (t == 63) bstart[NB] = inc;  // == K_CB
    }
    __syncthreads();                                   // B3

    // ---- scatter (value, original index) into bucket slots ----
    {
        int p;
        p = atomicAdd(&cursor[b0], 1); bval[p] = c4.x; bidx[p] = 4 * t + 0;
        p = atomicAdd(&cursor[b1], 1); bval[p] = c4.y; bidx[p] = 4 * t + 1;
        p = atomicAdd(&cursor[b2], 1); bval[p] = c4.z; bidx[p] = 4 * t + 2;
        p = atomicAdd(&cursor[b3], 1); bval[p] = c4.w; bidx[p] = 4 * t + 3;
    }
    __syncthreads();                                   // B4

    // ---- query ----
    int b = min(max((int)((x - GLO) * inv), 0), NB - 1);

    float best = __builtin_inff();
    int   bi   = 0x7fffffff;

    {   // own bucket
        int e = bstart[b + 1];
        for (int i = bstart[b]; i < e; ++i) {
            float d = dsq(x, bval[i]);
            int idx = bidx[i];
            if (d < best)                   { best = d; bi = idx; }
            else if (d == best && idx < bi) { bi = idx; }
        }
    }

    int  dl = b - 1, dr = b + 1;
    bool goL = (dl >= 0);
    bool goR = (dr < NB);
    while (goL || goR) {
        if (goL) {
            // conservative upper bound on bucket dl's contents (+1 bucket slack)
            float edge = GLO + (float)(dl + 2) * wdt;
            float gap  = x - edge;
            if (gap > 0.0f && gap * gap > best) {
                goL = false;
            } else {
                int e = bstart[dl + 1];
                for (int i = bstart[dl]; i < e; ++i) {
                    float d = dsq(x, bval[i]);
                    int idx = bidx[i];
                    if (d < best)                   { best = d; bi = idx; }
                    else if (d == best && idx < bi) { bi = idx; }
                }
                if (--dl < 0) goL = false;
            }
        }
        if (goR) {
            // conservative lower bound on bucket dr's contents (-1 bucket slack)
            float edge = GLO + (float)(dr - 1) * wdt;
            float gap  = edge - x;
            if (gap > 0.0f && gap * gap > best) {
                goR = false;
            } else {
                int e = bstart[dr + 1];
                for (int i = bstart[dr]; i < e; ++i) {
                    float d = dsq(x, bval[i]);
                    int idx = bidx[i];
                    if (d < best)                   { best = d; bi = idx; }
                    else if (d == best && idx < bi) { bi = idx; }
                }
                if (++dr >= NB) goR = false;
            }
        }
    }
    if (bi == 0x7fffffff) bi = 0;   // NaN-x: matches np.argmin on all-NaN row
    out[gid] = bi;

    if (gid == 0) out[N_W] = y[0];
}

extern "C" void kernel_launch(void* const* d_in, const int* in_sizes, int n_in,
                              void* d_out, int out_size, void* d_ws, size_t ws_size,
                              hipStream_t stream) {
    const float* w  = (const float*)d_in[0];
    const float* cb = (const float*)d_in[1]; // (K,1) contiguous == K floats
    const int*   y  = (const int*)d_in[2];
    int* out = (int*)d_out;

    // ONE launch (per-launch overhead ~14 us dominates multi-kernel plans);
    // d_ws untouched (poison-fill serialization, R2 evidence).
    (void)d_ws; (void)ws_size;

    vq_grid_kernel<<<GRID, BLK, 0, stream>>>(w, cb, y, out);
}